// Round 1
// baseline (3059.150 us; speedup 1.0000x reference)
//
#include <hip/hip_runtime.h>
#include <math.h>

#define B_NUM 2
#define S_LEN 4096
#define D_DIM 1024
#define H_NUM 16
#define DK    64

// ---------------------------------------------------------------------------
// GEMM: C[M,N] = A[M,K] @ W[N,K]^T   (both A and W are row-major over K)
// BM=BN=64, BK=16, 256 threads, each thread computes a 4x4 micro-tile.
// LDS layout [k][m] with +4 pad: inner-loop reads are broadcast (As) or
// 2-way aliased (Ws) -> conflict-free per m136.
// ---------------------------------------------------------------------------
__global__ __launch_bounds__(256) void gemm_abt(
    const float* __restrict__ A, const float* __restrict__ W,
    float* __restrict__ C, int M, int N, int K)
{
    __shared__ float As[16][68];
    __shared__ float Ws[16][68];

    const int tid = threadIdx.x;
    const int tx = tid & 15;          // 0..15 -> N direction
    const int ty = tid >> 4;          // 0..15 -> M direction
    const int m0 = blockIdx.y * 64;
    const int n0 = blockIdx.x * 64;

    const int lrow = tid >> 2;        // 0..63
    const int lk4  = (tid & 3) * 4;   // 0,4,8,12

    float acc[4][4] = {};

    for (int k0 = 0; k0 < K; k0 += 16) {
        const float4 av = *(const float4*)(A + (size_t)(m0 + lrow) * K + k0 + lk4);
        const float4 wv = *(const float4*)(W + (size_t)(n0 + lrow) * K + k0 + lk4);
        __syncthreads();   // previous iteration's reads complete
        As[lk4 + 0][lrow] = av.x; As[lk4 + 1][lrow] = av.y;
        As[lk4 + 2][lrow] = av.z; As[lk4 + 3][lrow] = av.w;
        Ws[lk4 + 0][lrow] = wv.x; Ws[lk4 + 1][lrow] = wv.y;
        Ws[lk4 + 2][lrow] = wv.z; Ws[lk4 + 3][lrow] = wv.w;
        __syncthreads();
        #pragma unroll
        for (int kk = 0; kk < 16; ++kk) {
            float a[4], w[4];
            #pragma unroll
            for (int i = 0; i < 4; ++i) a[i] = As[kk][ty * 4 + i];
            #pragma unroll
            for (int j = 0; j < 4; ++j) w[j] = Ws[kk][tx * 4 + j];
            #pragma unroll
            for (int i = 0; i < 4; ++i)
                #pragma unroll
                for (int j = 0; j < 4; ++j)
                    acc[i][j] = fmaf(a[i], w[j], acc[i][j]);
        }
    }

    #pragma unroll
    for (int i = 0; i < 4; ++i) {
        float4 r = make_float4(acc[i][0], acc[i][1], acc[i][2], acc[i][3]);
        *(float4*)(C + (size_t)(m0 + ty * 4 + i) * N + n0 + tx * 4) = r;
    }
}

// ---------------------------------------------------------------------------
// Flash attention, fp32, one block per (Q-tile of 64 rows, head, batch).
// BR=BC=64. 256 threads as 16x16; thread (tx,ty) owns a 4x4 tile of S and O.
// Row stats (m,l) via width-16 __shfl_xor (the 16 lanes of a row are
// contiguous in the wave). P round-trips through LDS (shares KsT's buffer).
// LDS: Qs 17408 + KP 16384 + Vs 16384 = 50176 B  (< 64 KB, 3 blocks/CU).
// ---------------------------------------------------------------------------
__global__ __launch_bounds__(256) void flash_attn(
    const float* __restrict__ q, const float* __restrict__ k,
    const float* __restrict__ v, float* __restrict__ heads)
{
    __shared__ float Qs[64][68];   // [row][dk]   stride 68 -> 4-distinct-bank rows
    __shared__ float KP[64][64];   // KsT [dk][col] during S; Ps [row][col] during PV
    __shared__ float Vs[64][64];   // [col][dk]

    const int tid = threadIdx.x;
    const int tx = tid & 15;
    const int ty = tid >> 4;
    const int s0 = blockIdx.x * 64;
    const int h  = blockIdx.y;
    const int b  = blockIdx.z;
    const size_t base = (size_t)b * S_LEN * D_DIM + (size_t)h * DK;

    // stage Q tile (64 rows x 64 dk), float4, coalesced-ish
    {
        const int r = tid >> 2;
        const int cb = (tid & 3) * 16;
        #pragma unroll
        for (int it = 0; it < 4; ++it) {
            float4 qa = *(const float4*)(q + base + (size_t)(s0 + r) * D_DIM + cb + it * 4);
            *(float4*)&Qs[r][cb + it * 4] = qa;
        }
    }

    float o[4][4] = {};
    float mrow[4] = { -INFINITY, -INFINITY, -INFINITY, -INFINITY };
    float lrow[4] = {};

    for (int kt = 0; kt < S_LEN / 64; ++kt) {
        const int t0 = kt * 64;
        __syncthreads();   // previous PV reads of Vs/KP done
        // stage K (transposed into [dk][col]) and V ([col][dk])
        {
            const int r = tid >> 2;
            const int cb = (tid & 3) * 16;
            #pragma unroll
            for (int it = 0; it < 4; ++it) {
                float4 kv = *(const float4*)(k + base + (size_t)(t0 + r) * D_DIM + cb + it * 4);
                KP[cb + it * 4 + 0][r] = kv.x;
                KP[cb + it * 4 + 1][r] = kv.y;
                KP[cb + it * 4 + 2][r] = kv.z;
                KP[cb + it * 4 + 3][r] = kv.w;
                float4 vv = *(const float4*)(v + base + (size_t)(t0 + r) * D_DIM + cb + it * 4);
                *(float4*)&Vs[r][cb + it * 4] = vv;
            }
        }
        __syncthreads();

        // S = (Q K^T) * 1/8
        float s[4][4] = {};
        #pragma unroll 8
        for (int kk = 0; kk < 64; ++kk) {
            float qa[4], kb[4];
            #pragma unroll
            for (int i = 0; i < 4; ++i) qa[i] = Qs[ty * 4 + i][kk];   // broadcast
            #pragma unroll
            for (int j = 0; j < 4; ++j) kb[j] = KP[kk][tx * 4 + j];   // 2-way
            #pragma unroll
            for (int i = 0; i < 4; ++i)
                #pragma unroll
                for (int j = 0; j < 4; ++j)
                    s[i][j] = fmaf(qa[i], kb[j], s[i][j]);
        }

        // online softmax update
        float alpha[4];
        #pragma unroll
        for (int i = 0; i < 4; ++i) {
            float mx = -INFINITY;
            #pragma unroll
            for (int j = 0; j < 4; ++j) { s[i][j] *= 0.125f; mx = fmaxf(mx, s[i][j]); }
            #pragma unroll
            for (int off = 1; off < 16; off <<= 1) mx = fmaxf(mx, __shfl_xor(mx, off, 16));
            const float mn = fmaxf(mrow[i], mx);
            alpha[i] = __expf(mrow[i] - mn);      // exp(-inf)=0 on first tile
            float ps = 0.f;
            #pragma unroll
            for (int j = 0; j < 4; ++j) { float p = __expf(s[i][j] - mn); s[i][j] = p; ps += p; }
            #pragma unroll
            for (int off = 1; off < 16; off <<= 1) ps += __shfl_xor(ps, off, 16);
            lrow[i] = lrow[i] * alpha[i] + ps;
            mrow[i] = mn;
            #pragma unroll
            for (int j = 0; j < 4; ++j) o[i][j] *= alpha[i];
        }

        __syncthreads();   // everyone done reading KP as KsT
        #pragma unroll
        for (int i = 0; i < 4; ++i)
            #pragma unroll
            for (int j = 0; j < 4; ++j)
                KP[ty * 4 + i][tx * 4 + j] = s[i][j];   // KP now holds P
        __syncthreads();

        // O += P @ V
        #pragma unroll 8
        for (int cc = 0; cc < 64; ++cc) {
            float pv[4], vv[4];
            #pragma unroll
            for (int i = 0; i < 4; ++i) pv[i] = KP[ty * 4 + i][cc];   // broadcast
            #pragma unroll
            for (int j = 0; j < 4; ++j) vv[j] = Vs[cc][tx * 4 + j];   // 2-way
            #pragma unroll
            for (int i = 0; i < 4; ++i)
                #pragma unroll
                for (int j = 0; j < 4; ++j)
                    o[i][j] = fmaf(pv[i], vv[j], o[i][j]);
        }
    }

    // normalize and store
    #pragma unroll
    for (int i = 0; i < 4; ++i) {
        const float inv = 1.0f / lrow[i];
        float4 r = make_float4(o[i][0] * inv, o[i][1] * inv, o[i][2] * inv, o[i][3] * inv);
        *(float4*)(heads + base + (size_t)(s0 + ty * 4 + i) * D_DIM + tx * 4) = r;
    }
}

// ---------------------------------------------------------------------------
extern "C" void kernel_launch(void* const* d_in, const int* in_sizes, int n_in,
                              void* d_out, int out_size, void* d_ws, size_t ws_size,
                              hipStream_t stream) {
    const float* Q  = (const float*)d_in[0];
    const float* K  = (const float*)d_in[1];
    const float* V  = (const float*)d_in[2];
    const float* Wq = (const float*)d_in[3];
    const float* Wk = (const float*)d_in[4];
    const float* Wv = (const float*)d_in[5];
    const float* Wo = (const float*)d_in[6];
    float* out = (float*)d_out;

    const size_t BSD = (size_t)B_NUM * S_LEN * D_DIM;   // 8388608
    float* ws = (float*)d_ws;
    float* qp = ws;
    float* kp = ws + BSD;
    float* vp = ws + 2 * BSD;
    float* hp = ws + 3 * BSD;   // needs 128 MB of workspace

    const int M = B_NUM * S_LEN;   // 8192
    dim3 blk(256);
    dim3 gg(D_DIM / 64, M / 64);   // 16 x 128

    gemm_abt<<<gg, blk, 0, stream>>>(Q, Wq, qp, M, D_DIM, D_DIM);
    gemm_abt<<<gg, blk, 0, stream>>>(K, Wk, kp, M, D_DIM, D_DIM);
    gemm_abt<<<gg, blk, 0, stream>>>(V, Wv, vp, M, D_DIM, D_DIM);

    flash_attn<<<dim3(S_LEN / 64, H_NUM, B_NUM), blk, 0, stream>>>(qp, kp, vp, hp);

    gemm_abt<<<gg, blk, 0, stream>>>(hp, Wo, out, M, D_DIM, D_DIM);
}

// Round 2
// 917.191 us; speedup vs baseline: 3.3353x; 3.3353x over previous
//
#include <hip/hip_runtime.h>
#include <math.h>

#define B_NUM 2
#define S_LEN 4096
#define D_DIM 1024
#define H_NUM 16
#define DKH   64

typedef __attribute__((ext_vector_type(8))) short short8;   // 8 bf16 = 4 VGPR (MFMA A/B frag)
typedef __attribute__((ext_vector_type(4))) float f32x4;    // MFMA C/D frag

__device__ __forceinline__ unsigned short f2bf(float f) {
    unsigned int u = __float_as_uint(f);
    u = (u + 0x7FFFu + ((u >> 16) & 1u)) >> 16;   // RNE
    return (unsigned short)u;
}

// async global->LDS, 16B per lane. LDS layout MUST be wave-uniform-base + lane*16.
__device__ __forceinline__ void async_ld16(const unsigned short* g, unsigned short* l) {
    __builtin_amdgcn_global_load_lds(
        (const __attribute__((address_space(1))) unsigned int*)g,
        (__attribute__((address_space(3))) unsigned int*)l, 16, 0, 0);
}

// ---------------------------------------------------------------------------
// fp32 -> bf16 elementwise convert (n multiple of 2048)
// ---------------------------------------------------------------------------
__global__ __launch_bounds__(256) void f2b8(const float* __restrict__ x,
                                            unsigned short* __restrict__ y, int n) {
    int i = (blockIdx.x * 256 + threadIdx.x) * 8;
    if (i >= n) return;
    float4 a = *(const float4*)(x + i);
    float4 b = *(const float4*)(x + i + 4);
    unsigned short t[8] = { f2bf(a.x), f2bf(a.y), f2bf(a.z), f2bf(a.w),
                            f2bf(b.x), f2bf(b.y), f2bf(b.z), f2bf(b.w) };
    *(uint4*)(y + i) = *(const uint4*)t;
}

// ---------------------------------------------------------------------------
// m97-recipe bf16 GEMM: C[M,N] = scale * (A[M,K] @ W[N,K]^T)
// 128x128 tile, BK=32, 4 waves in 2x2, 4x4 MFMA tiles/wave (16x16x32 bf16).
// Staging via global_load_lds width=16, identity LDS layout [row][32] bf16.
// ---------------------------------------------------------------------------
template <int OUT_BF16>
__global__ __launch_bounds__(256) void gemm_bt(
    const unsigned short* __restrict__ A, const unsigned short* __restrict__ Wt,
    void* __restrict__ Cout, int M, int N, int K, float scale)
{
    __shared__ unsigned short As[128 * 32];
    __shared__ unsigned short Bs[128 * 32];

    const int tid  = threadIdx.x;
    const int lane = tid & 63;
    const int wave = tid >> 6;
    const int quad = lane >> 4;
    const int l15  = lane & 15;
    const int m0 = blockIdx.y * 128;
    const int n0 = blockIdx.x * 128;
    const int wm = (wave >> 1) * 64;
    const int wn = (wave & 1) * 64;

    const int c0 = tid, c1 = tid + 256;            // 16B chunks, 2 per thread per tile
    const unsigned short* A0 = A  + (size_t)(m0 + (c0 >> 2)) * K + (c0 & 3) * 8;
    const unsigned short* A1 = A  + (size_t)(m0 + (c1 >> 2)) * K + (c1 & 3) * 8;
    const unsigned short* W0 = Wt + (size_t)(n0 + (c0 >> 2)) * K + (c0 & 3) * 8;
    const unsigned short* W1 = Wt + (size_t)(n0 + (c1 >> 2)) * K + (c1 & 3) * 8;

    const f32x4 fzero = {0.f, 0.f, 0.f, 0.f};
    f32x4 acc[4][4];
    #pragma unroll
    for (int i = 0; i < 4; ++i)
        #pragma unroll
        for (int j = 0; j < 4; ++j) acc[i][j] = fzero;

    for (int k0 = 0; k0 < K; k0 += 32) {
        __syncthreads();                            // prior tile's ds_reads done
        async_ld16(A0 + k0, &As[c0 * 8]);
        async_ld16(A1 + k0, &As[c1 * 8]);
        async_ld16(W0 + k0, &Bs[c0 * 8]);
        async_ld16(W1 + k0, &Bs[c1 * 8]);
        __syncthreads();                            // drains vmcnt -> LDS visible

        short8 af[4], bfr[4];
        #pragma unroll
        for (int i = 0; i < 4; ++i)
            af[i] = *(const short8*)&As[(wm + i * 16 + l15) * 32 + quad * 8];
        #pragma unroll
        for (int j = 0; j < 4; ++j)
            bfr[j] = *(const short8*)&Bs[(wn + j * 16 + l15) * 32 + quad * 8];
        #pragma unroll
        for (int i = 0; i < 4; ++i)
            #pragma unroll
            for (int j = 0; j < 4; ++j)
                acc[i][j] = __builtin_amdgcn_mfma_f32_16x16x32_bf16(af[i], bfr[j], acc[i][j], 0, 0, 0);
    }

    // epilogue: C/D layout col=lane&15, row=quad*4+reg  [m89/m91]
    #pragma unroll
    for (int i = 0; i < 4; ++i)
        #pragma unroll
        for (int j = 0; j < 4; ++j)
            #pragma unroll
            for (int r = 0; r < 4; ++r) {
                const int row = m0 + wm + i * 16 + quad * 4 + r;
                const int col = n0 + wn + j * 16 + l15;
                const float vv = acc[i][j][r] * scale;
                if (OUT_BF16) ((unsigned short*)Cout)[(size_t)row * N + col] = f2bf(vv);
                else          ((float*)Cout)[(size_t)row * N + col] = vv;
            }
}

// ---------------------------------------------------------------------------
// MFMA flash attention (bf16 in, bf16 heads out), q pre-scaled by 1/8.
// One block per (128-row Q tile, head, batch). 4 waves x 32 Q-rows.
// BC=64 K/V chunks; K natural [64][72], V transposed [dk][72] (lane-rotated
// b16 writes: conflict-free), P round-trip in wave-private Ps rows -> only
// 2 barriers per chunk. K/V global prefetch into regs overlaps compute.
// LDS = (128*72 + 64*72 + 64*72 + 128*64)*2 = 53248 B -> 3 blocks/CU.
// ---------------------------------------------------------------------------
__global__ __launch_bounds__(256, 3) void flash_mfma(
    const unsigned short* __restrict__ q, const unsigned short* __restrict__ k,
    const unsigned short* __restrict__ v, unsigned short* __restrict__ hp)
{
    __shared__ unsigned short Qs[128 * 72];
    __shared__ unsigned short Ks[64 * 72];
    __shared__ unsigned short Vt[64 * 72];   // [dk][key]
    __shared__ unsigned short Ps[128 * 64];  // wave-private rows

    const int tid  = threadIdx.x;
    const int lane = tid & 63;
    const int wave = tid >> 6;
    const int quad = lane >> 4;
    const int l15  = lane & 15;
    const int s0 = blockIdx.x * 128;
    const int h  = blockIdx.y;
    const int b  = blockIdx.z;
    const size_t base = (size_t)b * S_LEN * D_DIM + (size_t)h * DKH;

    // stage Q tile: 128 rows x 64 dk
    #pragma unroll
    for (int it = 0; it < 4; ++it) {
        const int g = tid + it * 256;
        const int r = g >> 3, cb = (g & 7) * 8;
        uint4 val = *(const uint4*)(q + base + (size_t)(s0 + r) * D_DIM + cb);
        *(uint4*)&Qs[r * 72 + cb] = val;
    }

    const f32x4 fzero = {0.f, 0.f, 0.f, 0.f};
    f32x4 o[2][4];
    float mrow[2][4], lrow[2][4];
    #pragma unroll
    for (int i = 0; i < 2; ++i)
        #pragma unroll
        for (int r = 0; r < 4; ++r) { mrow[i][r] = -INFINITY; lrow[i][r] = 0.f; }
    #pragma unroll
    for (int i = 0; i < 2; ++i)
        #pragma unroll
        for (int j = 0; j < 4; ++j) o[i][j] = fzero;

    uint4 kpre[2], vpre[2];
    auto load_kv = [&](int t0) {
        #pragma unroll
        for (int it = 0; it < 2; ++it) {
            const int g = tid + it * 256;
            const int r = g >> 3, cb = (g & 7) * 8;
            const size_t off = base + (size_t)(t0 + r) * D_DIM + cb;
            kpre[it] = *(const uint4*)(k + off);
            vpre[it] = *(const uint4*)(v + off);
        }
    };
    load_kv(0);

    for (int t0 = 0; t0 < S_LEN; t0 += 64) {
        __syncthreads();   // prior chunk's Ks/Vt reads done (also orders Q staging)
        #pragma unroll
        for (int it = 0; it < 2; ++it) {
            const int g = tid + it * 256;
            const int r = g >> 3, cb = (g & 7) * 8;
            *(uint4*)&Ks[r * 72 + cb] = kpre[it];
            union { uint4 u; unsigned short s[8]; } tv; tv.u = vpre[it];
            #pragma unroll
            for (int jj = 0; jj < 8; ++jj) {
                const int j = (jj + (tid & 7)) & 7;   // rotation -> banks spread
                Vt[(cb + j) * 72 + r] = tv.s[j];
            }
        }
        __syncthreads();
        if (t0 + 64 < S_LEN) load_kv(t0 + 64);   // overlaps with compute below

        // S = q k^T  (scale already in q)
        f32x4 s[2][4];
        #pragma unroll
        for (int i = 0; i < 2; ++i)
            #pragma unroll
            for (int j = 0; j < 4; ++j) s[i][j] = fzero;
        #pragma unroll
        for (int kk = 0; kk < 2; ++kk) {
            short8 af[2], bfr[4];
            #pragma unroll
            for (int i = 0; i < 2; ++i)
                af[i] = *(const short8*)&Qs[(wave * 32 + i * 16 + l15) * 72 + kk * 32 + quad * 8];
            #pragma unroll
            for (int j = 0; j < 4; ++j)
                bfr[j] = *(const short8*)&Ks[(j * 16 + l15) * 72 + kk * 32 + quad * 8];
            #pragma unroll
            for (int i = 0; i < 2; ++i)
                #pragma unroll
                for (int j = 0; j < 4; ++j)
                    s[i][j] = __builtin_amdgcn_mfma_f32_16x16x32_bf16(af[i], bfr[j], s[i][j], 0, 0, 0);
        }

        // online softmax: row = quad*4+r, reduce across 16 lanes of the quad
        #pragma unroll
        for (int i = 0; i < 2; ++i)
            #pragma unroll
            for (int r = 0; r < 4; ++r) {
                float mx = fmaxf(fmaxf(s[i][0][r], s[i][1][r]), fmaxf(s[i][2][r], s[i][3][r]));
                #pragma unroll
                for (int off = 1; off < 16; off <<= 1) mx = fmaxf(mx, __shfl_xor(mx, off));
                const float mn = fmaxf(mrow[i][r], mx);
                const float al = __expf(mrow[i][r] - mn);
                mrow[i][r] = mn;
                float ps = 0.f;
                #pragma unroll
                for (int j = 0; j < 4; ++j) {
                    const float p = __expf(s[i][j][r] - mn);
                    s[i][j][r] = p; ps += p;
                }
                #pragma unroll
                for (int off = 1; off < 16; off <<= 1) ps += __shfl_xor(ps, off);
                lrow[i][r] = lrow[i][r] * al + ps;
                #pragma unroll
                for (int j = 0; j < 4; ++j) o[i][j][r] *= al;
            }

        // P -> LDS (C/D layout -> A layout transform; wave-private rows, no barrier)
        #pragma unroll
        for (int i = 0; i < 2; ++i)
            #pragma unroll
            for (int j = 0; j < 4; ++j)
                #pragma unroll
                for (int r = 0; r < 4; ++r)
                    Ps[(wave * 32 + i * 16 + quad * 4 + r) * 64 + j * 16 + l15] = f2bf(s[i][j][r]);

        // O += P @ V
        #pragma unroll
        for (int kk = 0; kk < 2; ++kk) {
            short8 pf[2], vf[4];
            #pragma unroll
            for (int i = 0; i < 2; ++i)
                pf[i] = *(const short8*)&Ps[(wave * 32 + i * 16 + l15) * 64 + kk * 32 + quad * 8];
            #pragma unroll
            for (int j = 0; j < 4; ++j)
                vf[j] = *(const short8*)&Vt[(j * 16 + l15) * 72 + kk * 32 + quad * 8];
            #pragma unroll
            for (int i = 0; i < 2; ++i)
                #pragma unroll
                for (int j = 0; j < 4; ++j)
                    o[i][j] = __builtin_amdgcn_mfma_f32_16x16x32_bf16(pf[i], vf[j], o[i][j], 0, 0, 0);
        }
    }

    // normalize + store heads (bf16)
    #pragma unroll
    for (int i = 0; i < 2; ++i)
        #pragma unroll
        for (int r = 0; r < 4; ++r) {
            const float inv = 1.f / lrow[i][r];
            const int row = s0 + wave * 32 + i * 16 + quad * 4 + r;
            #pragma unroll
            for (int j = 0; j < 4; ++j)
                hp[base + (size_t)row * D_DIM + j * 16 + l15] = f2bf(o[i][j][r] * inv);
        }
}

// ---------------------------------------------------------------------------
extern "C" void kernel_launch(void* const* d_in, const int* in_sizes, int n_in,
                              void* d_out, int out_size, void* d_ws, size_t ws_size,
                              hipStream_t stream) {
    const float* Q  = (const float*)d_in[0];
    const float* K  = (const float*)d_in[1];
    const float* V  = (const float*)d_in[2];
    const float* Wq = (const float*)d_in[3];
    const float* Wk = (const float*)d_in[4];
    const float* Wv = (const float*)d_in[5];
    const float* Wo = (const float*)d_in[6];

    const int NBSD = 8388608;   // B*S*D
    const int NW   = 1048576;   // D*D

    unsigned short* Qb  = (unsigned short*)d_ws;
    unsigned short* Kb  = Qb  + NBSD;
    unsigned short* Vb  = Kb  + NBSD;
    unsigned short* Wqb = Vb  + NBSD;
    unsigned short* Wkb = Wqb + NW;
    unsigned short* Wvb = Wkb + NW;
    unsigned short* Wob = Wvb + NW;
    unsigned short* qp  = Wob + NW;
    unsigned short* kp  = qp  + NBSD;
    unsigned short* vp  = kp  + NBSD;
    unsigned short* hb  = vp  + NBSD;   // total 125.8 MB

    f2b8<<<NBSD / 2048, 256, 0, stream>>>(Q, Qb, NBSD);
    f2b8<<<NBSD / 2048, 256, 0, stream>>>(K, Kb, NBSD);
    f2b8<<<NBSD / 2048, 256, 0, stream>>>(V, Vb, NBSD);
    f2b8<<<NW / 2048, 256, 0, stream>>>(Wq, Wqb, NW);
    f2b8<<<NW / 2048, 256, 0, stream>>>(Wk, Wkb, NW);
    f2b8<<<NW / 2048, 256, 0, stream>>>(Wv, Wvb, NW);
    f2b8<<<NW / 2048, 256, 0, stream>>>(Wo, Wob, NW);

    const int M = B_NUM * S_LEN;   // 8192
    dim3 gg(D_DIM / 128, M / 128); // 8 x 64
    gemm_bt<1><<<gg, 256, 0, stream>>>(Qb, Wqb, qp, M, D_DIM, D_DIM, 0.125f); // 1/sqrt(dk) folded
    gemm_bt<1><<<gg, 256, 0, stream>>>(Kb, Wkb, kp, M, D_DIM, D_DIM, 1.0f);
    gemm_bt<1><<<gg, 256, 0, stream>>>(Vb, Wvb, vp, M, D_DIM, D_DIM, 1.0f);

    flash_mfma<<<dim3(S_LEN / 128, H_NUM, B_NUM), 256, 0, stream>>>(qp, kp, vp, hb);

    gemm_bt<0><<<gg, 256, 0, stream>>>(hb, Wob, d_out, M, D_DIM, D_DIM, 1.0f);
}

// Round 3
// 844.953 us; speedup vs baseline: 3.6205x; 1.0855x over previous
//
#include <hip/hip_runtime.h>
#include <hip/hip_bf16.h>
#include <math.h>

#define B_NUM 2
#define S_LEN 4096
#define D_DIM 1024
#define H_NUM 16
#define DKH   64

typedef __attribute__((ext_vector_type(8))) short short8;   // 8 bf16 = 4 VGPR (MFMA A/B frag)
typedef __attribute__((ext_vector_type(4))) float f32x4;    // MFMA C/D frag

__device__ __forceinline__ unsigned short f2bf(float f) {
    unsigned int u = __float_as_uint(f);
    u = (u + 0x7FFFu + ((u >> 16) & 1u)) >> 16;   // RNE
    return (unsigned short)u;
}

// packed f32x2 -> bf16x2 (low = lo), RNE; lowers to v_cvt_pk_bf16_f32 on gfx950
__device__ __forceinline__ unsigned pk_bf16(float lo, float hi) {
    __hip_bfloat162 h = __float22bfloat162_rn(make_float2(lo, hi));
    unsigned u; __builtin_memcpy(&u, &h, 4); return u;
}

// DPP row-rotate (16-lane row), VALU-pipe cross-lane
template <int CTRL>
__device__ __forceinline__ float dpp_mov(float x) {
    return __builtin_bit_cast(float,
        __builtin_amdgcn_update_dpp(0, __builtin_bit_cast(int, x), CTRL, 0xF, 0xF, false));
}
__device__ __forceinline__ float rmax16(float x) {   // max across the 16 lanes of a row
    x = fmaxf(x, dpp_mov<0x121>(x));   // row_ror:1
    x = fmaxf(x, dpp_mov<0x122>(x));   // row_ror:2
    x = fmaxf(x, dpp_mov<0x124>(x));   // row_ror:4
    x = fmaxf(x, dpp_mov<0x128>(x));   // row_ror:8
    return x;
}
__device__ __forceinline__ float rsum16(float x) {
    x += dpp_mov<0x121>(x);
    x += dpp_mov<0x122>(x);
    x += dpp_mov<0x124>(x);
    x += dpp_mov<0x128>(x);
    return x;
}

// async global->LDS, 16B per lane (GEMM staging)
__device__ __forceinline__ void async_ld16(const unsigned short* g, unsigned short* l) {
    __builtin_amdgcn_global_load_lds(
        (const __attribute__((address_space(1))) unsigned int*)g,
        (__attribute__((address_space(3))) unsigned int*)l, 16, 0, 0);
}

// ---------------------------------------------------------------------------
// fp32 -> bf16 elementwise convert (n multiple of 2048)
// ---------------------------------------------------------------------------
__global__ __launch_bounds__(256) void f2b8(const float* __restrict__ x,
                                            unsigned short* __restrict__ y, int n) {
    int i = (blockIdx.x * 256 + threadIdx.x) * 8;
    if (i >= n) return;
    float4 a = *(const float4*)(x + i);
    float4 b = *(const float4*)(x + i + 4);
    unsigned t[4] = { pk_bf16(a.x, a.y), pk_bf16(a.z, a.w),
                      pk_bf16(b.x, b.y), pk_bf16(b.z, b.w) };
    *(uint4*)(y + i) = *(const uint4*)t;
}

// ---------------------------------------------------------------------------
// m97-recipe bf16 GEMM: C[M,N] = scale * (A[M,K] @ W[N,K]^T)
// 128x128 tile, BK=32, 4 waves in 2x2, 4x4 MFMA tiles/wave (16x16x32 bf16).
// ---------------------------------------------------------------------------
template <int OUT_BF16>
__global__ __launch_bounds__(256) void gemm_bt(
    const unsigned short* __restrict__ A, const unsigned short* __restrict__ Wt,
    void* __restrict__ Cout, int M, int N, int K, float scale)
{
    __shared__ unsigned short As[128 * 32];
    __shared__ unsigned short Bs[128 * 32];

    const int tid  = threadIdx.x;
    const int lane = tid & 63;
    const int wave = tid >> 6;
    const int quad = lane >> 4;
    const int l15  = lane & 15;
    const int m0 = blockIdx.y * 128;
    const int n0 = blockIdx.x * 128;
    const int wm = (wave >> 1) * 64;
    const int wn = (wave & 1) * 64;

    const int c0 = tid, c1 = tid + 256;
    const unsigned short* A0 = A  + (size_t)(m0 + (c0 >> 2)) * K + (c0 & 3) * 8;
    const unsigned short* A1 = A  + (size_t)(m0 + (c1 >> 2)) * K + (c1 & 3) * 8;
    const unsigned short* W0 = Wt + (size_t)(n0 + (c0 >> 2)) * K + (c0 & 3) * 8;
    const unsigned short* W1 = Wt + (size_t)(n0 + (c1 >> 2)) * K + (c1 & 3) * 8;

    const f32x4 fzero = {0.f, 0.f, 0.f, 0.f};
    f32x4 acc[4][4];
    #pragma unroll
    for (int i = 0; i < 4; ++i)
        #pragma unroll
        for (int j = 0; j < 4; ++j) acc[i][j] = fzero;

    for (int k0 = 0; k0 < K; k0 += 32) {
        __syncthreads();
        async_ld16(A0 + k0, &As[c0 * 8]);
        async_ld16(A1 + k0, &As[c1 * 8]);
        async_ld16(W0 + k0, &Bs[c0 * 8]);
        async_ld16(W1 + k0, &Bs[c1 * 8]);
        __syncthreads();

        short8 af[4], bfr[4];
        #pragma unroll
        for (int i = 0; i < 4; ++i)
            af[i] = *(const short8*)&As[(wm + i * 16 + l15) * 32 + quad * 8];
        #pragma unroll
        for (int j = 0; j < 4; ++j)
            bfr[j] = *(const short8*)&Bs[(wn + j * 16 + l15) * 32 + quad * 8];
        #pragma unroll
        for (int i = 0; i < 4; ++i)
            #pragma unroll
            for (int j = 0; j < 4; ++j)
                acc[i][j] = __builtin_amdgcn_mfma_f32_16x16x32_bf16(af[i], bfr[j], acc[i][j], 0, 0, 0);
    }

    #pragma unroll
    for (int i = 0; i < 4; ++i)
        #pragma unroll
        for (int j = 0; j < 4; ++j)
            #pragma unroll
            for (int r = 0; r < 4; ++r) {
                const int row = m0 + wm + i * 16 + quad * 4 + r;
                const int col = n0 + wn + j * 16 + l15;
                const float vv = acc[i][j][r] * scale;
                if (OUT_BF16) ((unsigned short*)Cout)[(size_t)row * N + col] = f2bf(vv);
                else          ((float*)Cout)[(size_t)row * N + col] = vv;
            }
}

// ---------------------------------------------------------------------------
// MFMA flash attention v2. BR=256 (wave owns 64 q-rows), BC=64.
// Q and K fragments loaded DIRECTLY from global (L2) - no Qs/Ks LDS.
// Vt [dk][key] and Ps [qrow][key] in LDS with XOR swizzle:
//   physical_chunk(16B) = logical_chunk ^ (row & 7)  -> conflict-free b128.
// Softmax reductions via DPP row_ror (VALU pipe, no LDS traffic).
// exp2 domain: q pre-scaled by (1/8)*log2(e) in the q-projection.
// LDS = 8 KB (Vt) + 32 KB (Ps, wave-private rows) = 40 KB; grid 512 = 2/CU.
// ---------------------------------------------------------------------------
__global__ __launch_bounds__(256, 2) void flash_mfma(
    const unsigned short* __restrict__ q, const unsigned short* __restrict__ k,
    const unsigned short* __restrict__ v, unsigned short* __restrict__ hp)
{
    __shared__ unsigned short Vt[64 * 64];    // [dk][key] swizzled
    __shared__ unsigned short Ps[256 * 64];   // [qrow][key] swizzled, wave-private rows

    const int tid  = threadIdx.x;
    const int lane = tid & 63;
    const int wave = tid >> 6;
    const int quad = lane >> 4;
    const int l15  = lane & 15;
    const int s0 = blockIdx.x * 256;
    const size_t base = (size_t)blockIdx.z * ((size_t)S_LEN * D_DIM) + (size_t)blockIdx.y * DKH;

    // Q fragments: 64 rows per wave, direct global. 32 VGPR, loaded once.
    short8 qf[4][2];
    #pragma unroll
    for (int i = 0; i < 4; ++i)
        #pragma unroll
        for (int kk = 0; kk < 2; ++kk)
            qf[i][kk] = *(const short8*)(q + base +
                (size_t)(s0 + wave * 64 + i * 16 + l15) * D_DIM + kk * 32 + quad * 8);

    const f32x4 fzero = {0.f, 0.f, 0.f, 0.f};
    f32x4 o[4][4];
    float mrow[4][4], lrow[4][4];
    #pragma unroll
    for (int i = 0; i < 4; ++i)
        #pragma unroll
        for (int r = 0; r < 4; ++r) { mrow[i][r] = -INFINITY; lrow[i][r] = 0.f; }
    #pragma unroll
    for (int i = 0; i < 4; ++i)
        #pragma unroll
        for (int j = 0; j < 4; ++j) o[i][j] = fzero;

    const int vr  = tid >> 3;          // staging row (key) 0..31 (+32 for it=1)
    const int vcb = (tid & 7) * 8;     // staging dk base

    uint4 vpre[2];
    #pragma unroll
    for (int it = 0; it < 2; ++it)
        vpre[it] = *(const uint4*)(v + base + (size_t)(vr + it * 32) * D_DIM + vcb);

    for (int t0 = 0; t0 < S_LEN; t0 += 64) {
        // K fragments for this chunk: direct global, issued before the barrier
        short8 bfr[2][4];
        #pragma unroll
        for (int kk = 0; kk < 2; ++kk)
            #pragma unroll
            for (int j = 0; j < 4; ++j)
                bfr[kk][j] = *(const short8*)(k + base +
                    (size_t)(t0 + j * 16 + l15) * D_DIM + kk * 32 + quad * 8);

        __syncthreads();   // prior chunk's Vt reads complete
        #pragma unroll
        for (int it = 0; it < 2; ++it) {
            const int r = vr + it * 32;
            union { uint4 u; unsigned short s[8]; } tv; tv.u = vpre[it];
            #pragma unroll
            for (int jj = 0; jj < 8; ++jj) {
                const int j  = (jj + (tid & 7)) & 7;           // bank rotation
                const int dk = vcb + j;
                Vt[dk * 64 + (((r >> 3) ^ (dk & 7)) << 3) + (r & 7)] = tv.s[j];
            }
        }
        __syncthreads();
        if (t0 + 64 < S_LEN) {
            #pragma unroll
            for (int it = 0; it < 2; ++it)
                vpre[it] = *(const uint4*)(v + base + (size_t)(t0 + 64 + vr + it * 32) * D_DIM + vcb);
        }

        // ---- S = q k^T in halves of 32 q-rows (keeps s regs at 32 VGPR) ----
        #pragma unroll
        for (int ih = 0; ih < 2; ++ih) {
            f32x4 s2[2][4];
            #pragma unroll
            for (int ii = 0; ii < 2; ++ii)
                #pragma unroll
                for (int j = 0; j < 4; ++j) s2[ii][j] = fzero;
            #pragma unroll
            for (int kk = 0; kk < 2; ++kk)
                #pragma unroll
                for (int ii = 0; ii < 2; ++ii)
                    #pragma unroll
                    for (int j = 0; j < 4; ++j)
                        s2[ii][j] = __builtin_amdgcn_mfma_f32_16x16x32_bf16(
                            qf[ih * 2 + ii][kk], bfr[kk][j], s2[ii][j], 0, 0, 0);

            // online softmax (base-2 domain), DPP row reductions
            #pragma unroll
            for (int ii = 0; ii < 2; ++ii) {
                const int i = ih * 2 + ii;
                #pragma unroll
                for (int r = 0; r < 4; ++r) {
                    float mx = fmaxf(fmaxf(s2[ii][0][r], s2[ii][1][r]),
                                     fmaxf(s2[ii][2][r], s2[ii][3][r]));
                    mx = rmax16(mx);
                    const float mn = fmaxf(mrow[i][r], mx);
                    const float al = __builtin_amdgcn_exp2f(mrow[i][r] - mn);
                    mrow[i][r] = mn;
                    float ps = 0.f;
                    #pragma unroll
                    for (int j = 0; j < 4; ++j) {
                        const float p = __builtin_amdgcn_exp2f(s2[ii][j][r] - mn);
                        s2[ii][j][r] = p; ps += p;
                    }
                    ps = rsum16(ps);
                    lrow[i][r] = lrow[i][r] * al + ps;
                    #pragma unroll
                    for (int j = 0; j < 4; ++j) o[i][j][r] *= al;
                }
                // P -> Ps (wave-private rows, swizzled; packed converts)
                const int rw = wave * 64 + i * 16 + quad * 4;
                #pragma unroll
                for (int j = 0; j < 4; ++j) {
                    const int col = j * 16 + l15;
                    const int c   = col >> 3, w7 = col & 7;
                    #pragma unroll
                    for (int rp = 0; rp < 2; ++rp) {
                        const unsigned u = pk_bf16(s2[ii][j][2 * rp], s2[ii][j][2 * rp + 1]);
                        const int r0 = rw + 2 * rp, r1 = r0 + 1;
                        Ps[r0 * 64 + ((c ^ (r0 & 7)) << 3) + w7] = (unsigned short)u;
                        Ps[r1 * 64 + ((c ^ (r1 & 7)) << 3) + w7] = (unsigned short)(u >> 16);
                    }
                }
            }
        }

        // ---- O += P @ V ----
        #pragma unroll
        for (int kk = 0; kk < 2; ++kk) {
            short8 vf[4];
            #pragma unroll
            for (int j = 0; j < 4; ++j)
                vf[j] = *(const short8*)&Vt[(j * 16 + l15) * 64 + (((kk * 4 + quad) ^ (l15 & 7)) << 3)];
            #pragma unroll
            for (int i = 0; i < 4; ++i) {
                const int row = wave * 64 + i * 16 + l15;
                short8 pf = *(const short8*)&Ps[row * 64 + (((kk * 4 + quad) ^ (l15 & 7)) << 3)];
                #pragma unroll
                for (int j = 0; j < 4; ++j)
                    o[i][j] = __builtin_amdgcn_mfma_f32_16x16x32_bf16(pf, vf[j], o[i][j], 0, 0, 0);
            }
        }
    }

    // normalize + store heads (bf16)
    #pragma unroll
    for (int i = 0; i < 4; ++i)
        #pragma unroll
        for (int r = 0; r < 4; ++r) {
            const float inv = 1.f / lrow[i][r];
            const int row = s0 + wave * 64 + i * 16 + quad * 4 + r;
            #pragma unroll
            for (int j = 0; j < 4; ++j)
                hp[base + (size_t)row * D_DIM + j * 16 + l15] = f2bf(o[i][j][r] * inv);
        }
}

// ---------------------------------------------------------------------------
extern "C" void kernel_launch(void* const* d_in, const int* in_sizes, int n_in,
                              void* d_out, int out_size, void* d_ws, size_t ws_size,
                              hipStream_t stream) {
    const float* Q  = (const float*)d_in[0];
    const float* K  = (const float*)d_in[1];
    const float* V  = (const float*)d_in[2];
    const float* Wq = (const float*)d_in[3];
    const float* Wk = (const float*)d_in[4];
    const float* Wv = (const float*)d_in[5];
    const float* Wo = (const float*)d_in[6];

    const int NBSD = 8388608;   // B*S*D
    const int NW   = 1048576;   // D*D

    unsigned short* Qb  = (unsigned short*)d_ws;
    unsigned short* Kb  = Qb  + NBSD;
    unsigned short* Vb  = Kb  + NBSD;
    unsigned short* Wqb = Vb  + NBSD;
    unsigned short* Wkb = Wqb + NW;
    unsigned short* Wvb = Wkb + NW;
    unsigned short* Wob = Wvb + NW;
    unsigned short* qp  = Wob + NW;
    unsigned short* kp  = qp  + NBSD;
    unsigned short* vp  = kp  + NBSD;
    unsigned short* hb  = vp  + NBSD;   // total ~126 MB

    f2b8<<<NBSD / 2048, 256, 0, stream>>>(Q, Qb, NBSD);
    f2b8<<<NBSD / 2048, 256, 0, stream>>>(K, Kb, NBSD);
    f2b8<<<NBSD / 2048, 256, 0, stream>>>(V, Vb, NBSD);
    f2b8<<<NW / 2048, 256, 0, stream>>>(Wq, Wqb, NW);
    f2b8<<<NW / 2048, 256, 0, stream>>>(Wk, Wkb, NW);
    f2b8<<<NW / 2048, 256, 0, stream>>>(Wv, Wvb, NW);
    f2b8<<<NW / 2048, 256, 0, stream>>>(Wo, Wob, NW);

    const int M = B_NUM * S_LEN;   // 8192
    dim3 gg(D_DIM / 128, M / 128); // 8 x 64
    // q scale: (1/sqrt(dk)) * log2(e) -> softmax computed in exp2 domain
    gemm_bt<1><<<gg, 256, 0, stream>>>(Qb, Wqb, qp, M, D_DIM, D_DIM, 0.125f * 1.4426950408889634f);
    gemm_bt<1><<<gg, 256, 0, stream>>>(Kb, Wkb, kp, M, D_DIM, D_DIM, 1.0f);
    gemm_bt<1><<<gg, 256, 0, stream>>>(Vb, Wvb, vp, M, D_DIM, D_DIM, 1.0f);

    flash_mfma<<<dim3(S_LEN / 256, H_NUM, B_NUM), 256, 0, stream>>>(qp, kp, vp, hb);

    gemm_bt<0><<<gg, 256, 0, stream>>>(hb, Wob, d_out, M, D_DIM, D_DIM, 1.0f);
}